// Round 1
// baseline (253.188 us; speedup 1.0000x reference)
//
#include <hip/hip_runtime.h>
#include <hip/hip_bf16.h>
#include <stdint.h>

#define NB 4
#define NT 4096
#define NE 100
#define ND 64

typedef __attribute__((ext_vector_type(8))) short short8;
typedef __attribute__((ext_vector_type(4))) short short4_;
typedef __attribute__((ext_vector_type(4))) float float4_;

__device__ __forceinline__ unsigned short f2bf(float f) {
  union { float f; uint32_t u; } v; v.f = f;
  uint32_t u = v.u;
  u += 0x7fffu + ((u >> 16) & 1u);   // RNE
  return (unsigned short)(u >> 16);
}

__device__ __forceinline__ float fast_exp2(float x) {
#if __has_builtin(__builtin_amdgcn_exp2f)
  return __builtin_amdgcn_exp2f(x);
#else
  return exp2f(x);
#endif
}

// ---------------- projection: q = (x@Wq)*0.125*log2e, k = x@Wk, v^T = (x@Wv)^T
__global__ __launch_bounds__(256) void proj_kernel(
    const float* __restrict__ x, const float* __restrict__ Wq,
    const float* __restrict__ Wk, const float* __restrict__ Wv,
    unsigned short* __restrict__ Qb, unsigned short* __restrict__ Kb,
    unsigned short* __restrict__ Vt) {
  int tid  = blockIdx.x * 256 + threadIdx.x;
  int wave = tid >> 6;          // 0..4095, each wave does 4 rows
  int lane = tid & 63;          // = output dim d
  int r0   = wave << 2;
  const float* xr = x + (size_t)r0 * NE;
  float aq0=0,aq1=0,aq2=0,aq3=0;
  float ak0=0,ak1=0,ak2=0,ak3=0;
  float av0=0,av1=0,av2=0,av3=0;
  const float* wqp = Wq + lane;
  const float* wkp = Wk + lane;
  const float* wvp = Wv + lane;
  #pragma unroll 4
  for (int e = 0; e < NE; ++e) {
    float wq = wqp[e*ND], wk = wkp[e*ND], wv = wvp[e*ND];
    float x0 = xr[e], x1 = xr[NE+e], x2 = xr[2*NE+e], x3 = xr[3*NE+e];
    aq0 += x0*wq; ak0 += x0*wk; av0 += x0*wv;
    aq1 += x1*wq; ak1 += x1*wk; av1 += x1*wv;
    aq2 += x2*wq; ak2 += x2*wk; av2 += x2*wv;
    aq3 += x3*wq; ak3 += x3*wk; av3 += x3*wv;
  }
  const float QS = 0.125f * 1.44269504088896340736f; // scale * log2(e)
  float aqs[4] = {aq0,aq1,aq2,aq3};
  float aks[4] = {ak0,ak1,ak2,ak3};
  float avs[4] = {av0,av1,av2,av3};
  #pragma unroll
  for (int r = 0; r < 4; ++r) {
    int row = r0 + r;
    Qb[(size_t)row*ND + lane] = f2bf(aqs[r]*QS);
    Kb[(size_t)row*ND + lane] = f2bf(aks[r]);
    int b = row >> 12, t = row & (NT-1);
    Vt[(size_t)(b*ND + lane)*NT + t] = f2bf(avs[r]);
  }
}

// ---------------- causal flash attention, 1 wave per 16 q-rows
__global__ __launch_bounds__(64) void attn_kernel(
    const unsigned short* __restrict__ Qb,
    const unsigned short* __restrict__ Kb,
    const unsigned short* __restrict__ Vt,
    float* __restrict__ out) {
  __shared__ __align__(16) unsigned short Pbuf[16][72]; // +pad: conflict-light
  const int lane = threadIdx.x;
  const int wid  = blockIdx.x;
  const int b    = wid >> 8;
  const int q0   = (wid & 255) << 4;   // 16 q rows
  const int qrow = lane & 15;
  const int grp  = lane >> 4;

  const unsigned short* Qr = Qb + ((size_t)(b*NT + q0 + qrow))*ND + 8*grp;
  const short8 qf0 = *(const short8*)(Qr);
  const short8 qf1 = *(const short8*)(Qr + 32);

  float4_ Oacc0 = {0,0,0,0}, Oacc1 = {0,0,0,0}, Oacc2 = {0,0,0,0}, Oacc3 = {0,0,0,0};
  float m = -1e30f, lsum = 0.f;

  const int ntiles = ((q0 + 15) >> 6) + 1;     // kv tiles of 64
  const unsigned short* Kbase = Kb + (size_t)b*NT*ND;
  const unsigned short* Vtb   = Vt + (size_t)b*ND*NT;

  for (int tile = 0; tile < ntiles; ++tile) {
    const int kv0 = tile << 6;
    float4_ s[4];
    #pragma unroll
    for (int st = 0; st < 4; ++st) {
      const unsigned short* Krow = Kbase + (size_t)(kv0 + st*16 + qrow)*ND + 8*grp;
      short8 kf0 = *(const short8*)(Krow);
      short8 kf1 = *(const short8*)(Krow + 32);
      float4_ acc = {0,0,0,0};
      acc = __builtin_amdgcn_mfma_f32_16x16x32_bf16(kf0, qf0, acc, 0, 0, 0);
      acc = __builtin_amdgcn_mfma_f32_16x16x32_bf16(kf1, qf1, acc, 0, 0, 0);
      s[st] = acc;
    }
    if (tile == ntiles - 1) {
      #pragma unroll
      for (int st = 0; st < 4; ++st)
        #pragma unroll
        for (int r = 0; r < 4; ++r) {
          int kv = kv0 + st*16 + grp*4 + r;
          if (kv > q0 + qrow) s[st][r] = -1e30f;
        }
    }
    float tmax = -1e30f;
    #pragma unroll
    for (int st = 0; st < 4; ++st)
      #pragma unroll
      for (int r = 0; r < 4; ++r) tmax = fmaxf(tmax, s[st][r]);
    tmax = fmaxf(tmax, __shfl_xor(tmax, 16));
    tmax = fmaxf(tmax, __shfl_xor(tmax, 32));
    const float mnew  = fmaxf(m, tmax);
    const float alpha = fast_exp2(m - mnew);
    m = mnew;
    float psum = 0.f;
    #pragma unroll
    for (int st = 0; st < 4; ++st) {
      short4_ pv;
      #pragma unroll
      for (int r = 0; r < 4; ++r) {
        float p = fast_exp2(s[st][r] - mnew);
        psum += p;
        pv[r] = (short)f2bf(p);
      }
      *(short4_*)&Pbuf[qrow][st*16 + grp*4] = pv;
    }
    psum += __shfl_xor(psum, 16);
    psum += __shfl_xor(psum, 32);
    lsum = lsum * alpha + psum;

    #pragma unroll
    for (int r = 0; r < 4; ++r) {
      float ar = __shfl(alpha, grp*4 + r);
      Oacc0[r] *= ar; Oacc1[r] *= ar; Oacc2[r] *= ar; Oacc3[r] *= ar;
    }

    asm volatile("s_waitcnt lgkmcnt(0)" ::: "memory");

    short8 pf0 = *(const short8*)&Pbuf[qrow][8*grp];
    short8 pf1 = *(const short8*)&Pbuf[qrow][32 + 8*grp];
    const unsigned short* vr0 = Vtb + (size_t)(0*16 + qrow)*NT + kv0 + 8*grp;
    const unsigned short* vr1 = Vtb + (size_t)(1*16 + qrow)*NT + kv0 + 8*grp;
    const unsigned short* vr2 = Vtb + (size_t)(2*16 + qrow)*NT + kv0 + 8*grp;
    const unsigned short* vr3 = Vtb + (size_t)(3*16 + qrow)*NT + kv0 + 8*grp;
    Oacc0 = __builtin_amdgcn_mfma_f32_16x16x32_bf16(pf0, *(const short8*)vr0,      Oacc0, 0,0,0);
    Oacc0 = __builtin_amdgcn_mfma_f32_16x16x32_bf16(pf1, *(const short8*)(vr0+32), Oacc0, 0,0,0);
    Oacc1 = __builtin_amdgcn_mfma_f32_16x16x32_bf16(pf0, *(const short8*)vr1,      Oacc1, 0,0,0);
    Oacc1 = __builtin_amdgcn_mfma_f32_16x16x32_bf16(pf1, *(const short8*)(vr1+32), Oacc1, 0,0,0);
    Oacc2 = __builtin_amdgcn_mfma_f32_16x16x32_bf16(pf0, *(const short8*)vr2,      Oacc2, 0,0,0);
    Oacc2 = __builtin_amdgcn_mfma_f32_16x16x32_bf16(pf1, *(const short8*)(vr2+32), Oacc2, 0,0,0);
    Oacc3 = __builtin_amdgcn_mfma_f32_16x16x32_bf16(pf0, *(const short8*)vr3,      Oacc3, 0,0,0);
    Oacc3 = __builtin_amdgcn_mfma_f32_16x16x32_bf16(pf1, *(const short8*)(vr3+32), Oacc3, 0,0,0);
  }

  float* orow = out + ((size_t)b*NT + q0)*ND;
  #pragma unroll
  for (int r = 0; r < 4; ++r) {
    float inv = 1.f / __shfl(lsum, grp*4 + r);
    int qr = grp*4 + r;
    orow[qr*ND + 0*16 + qrow] = Oacc0[r]*inv;
    orow[qr*ND + 1*16 + qrow] = Oacc1[r]*inv;
    orow[qr*ND + 2*16 + qrow] = Oacc2[r]*inv;
    orow[qr*ND + 3*16 + qrow] = Oacc3[r]*inv;
  }
}

extern "C" void kernel_launch(void* const* d_in, const int* in_sizes, int n_in,
                              void* d_out, int out_size, void* d_ws, size_t ws_size,
                              hipStream_t stream) {
  const float* x  = (const float*)d_in[0];
  const float* Wq = (const float*)d_in[1];
  const float* Wk = (const float*)d_in[2];
  const float* Wv = (const float*)d_in[3];
  float* out = (float*)d_out;

  unsigned short* Qb = (unsigned short*)d_ws;                 // [B][T][64] bf16
  unsigned short* Kb = Qb + (size_t)NB*NT*ND;                 // [B][T][64] bf16
  unsigned short* Vt = Kb + (size_t)NB*NT*ND;                 // [B][64][T] bf16

  proj_kernel<<<dim3(1024), dim3(256), 0, stream>>>(x, Wq, Wk, Wv, Qb, Kb, Vt);
  attn_kernel<<<dim3(NB*256), dim3(64), 0, stream>>>(Qb, Kb, Vt, out);
}

// Round 3
// 162.110 us; speedup vs baseline: 1.5618x; 1.5618x over previous
//
#include <hip/hip_runtime.h>
#include <hip/hip_bf16.h>
#include <stdint.h>

#define NB 4
#define NT 4096
#define NE 100
#define ND 64

typedef __attribute__((ext_vector_type(8))) short short8;
typedef __attribute__((ext_vector_type(4))) short short4_;
typedef __attribute__((ext_vector_type(4))) float float4_;
typedef unsigned short ushort_t;

__device__ __forceinline__ unsigned short f2bf(float f) {
  union { float f; uint32_t u; } v; v.f = f;
  uint32_t u = v.u;
  u += 0x7fffu + ((u >> 16) & 1u);   // RNE
  return (unsigned short)(u >> 16);
}

__device__ __forceinline__ float fast_exp2(float x) {
#if __has_builtin(__builtin_amdgcn_exp2f)
  return __builtin_amdgcn_exp2f(x);
#else
  return exp2f(x);
#endif
}

// ---------------- projection ----------------
// q = (x@Wq)*0.125*log2e (log2-domain softmax), k = x@Wk, v^T via LDS transpose.
// Block = 256 thr = 4 waves, covers 16 rows. x staged in LDS (coalesced float4),
// V written transposed through LDS in 16B chunks (kills the 2B/8KB-stride scatter).
__global__ __launch_bounds__(256) void proj_kernel(
    const float* __restrict__ x, const float* __restrict__ Wq,
    const float* __restrict__ Wk, const float* __restrict__ Wv,
    ushort_t* __restrict__ Qb, ushort_t* __restrict__ Kb,
    ushort_t* __restrict__ Vt) {
  __shared__ float xs[16 * NE];          // 6.4 KB
  __shared__ ushort_t Vl[16][72];        // padded: transpose staging
  const int tid = threadIdx.x;
  const int r0  = blockIdx.x * 16;       // 16 rows per block

  { // stage x[16][100] -> LDS, coalesced
    const float4_* xsrc = (const float4_*)(x + (size_t)r0 * NE);
    float4_* xdst = (float4_*)xs;
    #pragma unroll
    for (int i = tid; i < 400; i += 256) xdst[i] = xsrc[i];
  }
  __syncthreads();

  const int wv = tid >> 6, lane = tid & 63;
  float aq[4] = {0,0,0,0}, ak[4] = {0,0,0,0}, av[4] = {0,0,0,0};
  const float* xw = xs + (wv * 4) * NE;

  #pragma unroll 4
  for (int e = 0; e < NE; ++e) {
    float wq  = Wq[e*ND + lane];
    float wk  = Wk[e*ND + lane];
    float wvv = Wv[e*ND + lane];
    #pragma unroll
    for (int j = 0; j < 4; ++j) {
      float xv = xw[j*NE + e];
      aq[j] += xv * wq; ak[j] += xv * wk; av[j] += xv * wvv;
    }
  }

  const float QS = 0.125f * 1.44269504088896340736f; // scale * log2(e)
  #pragma unroll
  for (int j = 0; j < 4; ++j) {
    int row = r0 + wv*4 + j;
    Qb[(size_t)row*ND + lane] = f2bf(aq[j] * QS);
    Kb[(size_t)row*ND + lane] = f2bf(ak[j]);
    Vl[wv*4 + j][lane] = f2bf(av[j]);
  }
  __syncthreads();

  if (tid < 128) { // transposed V write: 16B per thread, 32B contiguous per d
    int d = tid >> 1, half = tid & 1;
    short8 pk;
    #pragma unroll
    for (int k2 = 0; k2 < 8; ++k2) pk[k2] = (short)Vl[half*8 + k2][d];
    int b = r0 >> 12, tg = (r0 & (NT-1)) + half*8;
    *(short8*)(Vt + ((size_t)(b*ND + d))*NT + tg) = pk;
  }
}

// ---------------- causal flash attention ----------------
// Block = 256 thr = 4 waves, one 16-row q-tile. KV tiles (64 wide) split
// across the 4 waves (strided), each wave keeps private (m, l, O) online
// state with next-K register prefetch; partials combined through LDS.
__global__ __launch_bounds__(256) void attn_kernel(
    const ushort_t* __restrict__ Qb,
    const ushort_t* __restrict__ Kb,
    const ushort_t* __restrict__ Vt,
    float* __restrict__ out) {
  __shared__ __align__(16) ushort_t Pbuf[4][16][72];
  __shared__ float Om[4][16][64];
  __shared__ float Ml[4][16][2];

  const int tid  = threadIdx.x;
  const int w    = tid >> 6, lane = tid & 63;
  const int blk  = blockIdx.x;
  const int b    = blk >> 8;
  const int q0   = (255 - (blk & 255)) << 4;   // longest blocks dispatch first
  const int qrow = lane & 15;
  const int grp  = lane >> 4;

  const ushort_t* Qr = Qb + ((size_t)(b*NT + q0 + qrow))*ND + 8*grp;
  const short8 qf0 = *(const short8*)(Qr);
  const short8 qf1 = *(const short8*)(Qr + 32);

  const ushort_t* Kbase = Kb + (size_t)b*NT*ND;
  const ushort_t* Vtb   = Vt + (size_t)b*ND*NT;

  const int ntiles = (q0 >> 6) + 1;
  const int ntw    = (ntiles > w) ? ((ntiles - w + 3) >> 2) : 0;

  float4_ O0 = {0,0,0,0}, O1 = {0,0,0,0}, O2 = {0,0,0,0}, O3 = {0,0,0,0};
  float m = -1e30f, lsum = 0.f;

  short8 kc[8], kn[8], vf[8];
  { // preload this wave's first K tile (tile index w — always in-bounds memory)
    const ushort_t* kp = Kbase + (size_t)((w << 6) + qrow)*ND + 8*grp;
    #pragma unroll
    for (int st = 0; st < 4; ++st) {
      kc[st*2]   = *(const short8*)(kp + st*16*ND);
      kc[st*2+1] = *(const short8*)(kp + st*16*ND + 32);
    }
  }
  #pragma unroll
  for (int i = 0; i < 8; ++i) kn[i] = kc[i];

  for (int t = 0; t < ntw; ++t) {
    const int tg  = w + 4*t;
    const int kv0 = tg << 6;

    { // V loads first — consumed only after softmax, latency hides under it
      const ushort_t* vp = Vtb + (size_t)qrow*NT + kv0 + 8*grp;
      #pragma unroll
      for (int j = 0; j < 4; ++j) {
        vf[j*2]   = *(const short8*)(vp + (size_t)j*16*NT);
        vf[j*2+1] = *(const short8*)(vp + (size_t)j*16*NT + 32);
      }
    }
    if (t + 1 < ntw) { // prefetch next K tile for this wave
      const ushort_t* kp = Kbase + (size_t)(((w + 4*(t+1)) << 6) + qrow)*ND + 8*grp;
      #pragma unroll
      for (int st = 0; st < 4; ++st) {
        kn[st*2]   = *(const short8*)(kp + st*16*ND);
        kn[st*2+1] = *(const short8*)(kp + st*16*ND + 32);
      }
    }

    // S^T = K_tile · Q^T  (lane owns q-row q0+qrow; kv = kv0 + st*16 + grp*4 + r)
    float4_ s[4];
    #pragma unroll
    for (int st = 0; st < 4; ++st) {
      float4_ acc = {0,0,0,0};
      acc = __builtin_amdgcn_mfma_f32_16x16x32_bf16(kc[st*2],   qf0, acc, 0,0,0);
      acc = __builtin_amdgcn_mfma_f32_16x16x32_bf16(kc[st*2+1], qf1, acc, 0,0,0);
      s[st] = acc;
    }

    if (tg == ntiles - 1) { // only the diagonal tile violates causality
      #pragma unroll
      for (int st = 0; st < 4; ++st)
        #pragma unroll
        for (int r = 0; r < 4; ++r) {
          int kv = kv0 + st*16 + grp*4 + r;
          if (kv > q0 + qrow) s[st][r] = -1e30f;
        }
    }

    // online softmax (log2 domain; Q pre-scaled)
    float tmax = -1e30f;
    #pragma unroll
    for (int st = 0; st < 4; ++st)
      #pragma unroll
      for (int r = 0; r < 4; ++r) tmax = fmaxf(tmax, s[st][r]);
    tmax = fmaxf(tmax, __shfl_xor(tmax, 16));
    tmax = fmaxf(tmax, __shfl_xor(tmax, 32));
    const float mnew  = fmaxf(m, tmax);
    const float alpha = fast_exp2(m - mnew);
    m = mnew;

    float psum = 0.f;
    #pragma unroll
    for (int st = 0; st < 4; ++st) {
      short4_ pv;
      #pragma unroll
      for (int r = 0; r < 4; ++r) {
        float p = fast_exp2(s[st][r] - mnew);
        psum += p;
        pv[r] = (short)f2bf(p);
      }
      *(short4_*)&Pbuf[w][qrow][st*16 + grp*4] = pv;
    }
    psum += __shfl_xor(psum, 16);
    psum += __shfl_xor(psum, 32);
    lsum = lsum * alpha + psum;

    #pragma unroll
    for (int r = 0; r < 4; ++r) {
      float ar = __shfl(alpha, grp*4 + r);
      O0[r] *= ar; O1[r] *= ar; O2[r] *= ar; O3[r] *= ar;
    }

    asm volatile("s_waitcnt lgkmcnt(0)" ::: "memory");

    const short8 pf0 = *(const short8*)&Pbuf[w][qrow][8*grp];
    const short8 pf1 = *(const short8*)&Pbuf[w][qrow][32 + 8*grp];
    O0 = __builtin_amdgcn_mfma_f32_16x16x32_bf16(pf0, vf[0], O0, 0,0,0);
    O0 = __builtin_amdgcn_mfma_f32_16x16x32_bf16(pf1, vf[1], O0, 0,0,0);
    O1 = __builtin_amdgcn_mfma_f32_16x16x32_bf16(pf0, vf[2], O1, 0,0,0);
    O1 = __builtin_amdgcn_mfma_f32_16x16x32_bf16(pf1, vf[3], O1, 0,0,0);
    O2 = __builtin_amdgcn_mfma_f32_16x16x32_bf16(pf0, vf[4], O2, 0,0,0);
    O2 = __builtin_amdgcn_mfma_f32_16x16x32_bf16(pf1, vf[5], O2, 0,0,0);
    O3 = __builtin_amdgcn_mfma_f32_16x16x32_bf16(pf0, vf[6], O3, 0,0,0);
    O3 = __builtin_amdgcn_mfma_f32_16x16x32_bf16(pf1, vf[7], O3, 0,0,0);

    #pragma unroll
    for (int i = 0; i < 8; ++i) kc[i] = kn[i];
  }

  // ---- write per-wave partials (O rows are grp*4+r; cols j*16+qrow)
  #pragma unroll
  for (int r = 0; r < 4; ++r) {
    int row = grp*4 + r;
    Om[w][row][0*16 + qrow] = O0[r];
    Om[w][row][1*16 + qrow] = O1[r];
    Om[w][row][2*16 + qrow] = O2[r];
    Om[w][row][3*16 + qrow] = O3[r];
  }
  if (lane < 16) { Ml[w][lane][0] = m; Ml[w][lane][1] = lsum; }
  __syncthreads();

  // ---- combine 4 partials, divide, store (coalesced)
  const size_t qbase = (size_t)b*NT + q0;
  for (int e = tid; e < 1024; e += 256) {
    int row = e >> 6, d = e & 63;
    float M = Ml[0][row][0];
    M = fmaxf(M, Ml[1][row][0]);
    M = fmaxf(M, Ml[2][row][0]);
    M = fmaxf(M, Ml[3][row][0]);
    float ls = 0.f, os = 0.f;
    #pragma unroll
    for (int ww = 0; ww < 4; ++ww) {
      float sc = fast_exp2(Ml[ww][row][0] - M);
      ls += sc * Ml[ww][row][1];
      os += sc * Om[ww][row][d];
    }
    out[(qbase + row)*ND + d] = os / ls;
  }
}

extern "C" void kernel_launch(void* const* d_in, const int* in_sizes, int n_in,
                              void* d_out, int out_size, void* d_ws, size_t ws_size,
                              hipStream_t stream) {
  const float* x  = (const float*)d_in[0];
  const float* Wq = (const float*)d_in[1];
  const float* Wk = (const float*)d_in[2];
  const float* Wv = (const float*)d_in[3];
  float* out = (float*)d_out;

  ushort_t* Qb = (ushort_t*)d_ws;                 // [B][T][64] bf16
  ushort_t* Kb = Qb + (size_t)NB*NT*ND;           // [B][T][64] bf16
  ushort_t* Vt = Kb + (size_t)NB*NT*ND;           // [B][64][T] bf16

  proj_kernel<<<dim3(1024), dim3(256), 0, stream>>>(x, Wq, Wk, Wv, Qb, Kb, Vt);
  attn_kernel<<<dim3(NB*256), dim3(256), 0, stream>>>(Qb, Kb, Vt, out);
}

// Round 4
// 143.968 us; speedup vs baseline: 1.7586x; 1.1260x over previous
//
#include <hip/hip_runtime.h>
#include <hip/hip_bf16.h>
#include <stdint.h>

#define NB 4
#define NT 4096
#define NE 100
#define ND 64

typedef __attribute__((ext_vector_type(8))) short short8;
typedef __attribute__((ext_vector_type(4))) short short4_;
typedef __attribute__((ext_vector_type(4))) float float4_;
typedef unsigned short ushort_t;

__device__ __forceinline__ unsigned short f2bf(float f) {
  union { float f; uint32_t u; } v; v.f = f;
  uint32_t u = v.u;
  u += 0x7fffu + ((u >> 16) & 1u);   // RNE
  return (unsigned short)(u >> 16);
}

__device__ __forceinline__ float bf2f(short us) {
  union { uint32_t u; float f; } v;
  v.u = ((uint32_t)(unsigned short)us) << 16;
  return v.f;
}

__device__ __forceinline__ float fast_exp2(float x) {
#if __has_builtin(__builtin_amdgcn_exp2f)
  return __builtin_amdgcn_exp2f(x);
#else
  return exp2f(x);
#endif
}

// ---------------- projection ----------------
// q = (x@Wq)*0.125*log2e, k = x@Wk, v^T via LDS transpose.
// W staged ONCE per block into LDS as bf16 (kills the L1-thrashing global
// W reloads that dominated the 70us proj). Vl aliases xs (used after barrier).
__global__ __launch_bounds__(256) void proj_kernel(
    const float* __restrict__ x, const float* __restrict__ Wq,
    const float* __restrict__ Wk, const float* __restrict__ Wv,
    ushort_t* __restrict__ Qb, ushort_t* __restrict__ Kb,
    ushort_t* __restrict__ Vt) {
  __shared__ __align__(16) float xs[16 * NE];              // 6.4 KB
  __shared__ __align__(16) ushort_t Wl[3][25][64][4];      // 38.4 KB bf16
  ushort_t (*Vl)[72] = (ushort_t(*)[72])xs;                // alias (post-barrier)

  const int tid = threadIdx.x;
  const int r0  = blockIdx.x * 16;

  { // stage x[16][100] -> LDS, coalesced
    const float4_* xsrc = (const float4_*)(x + (size_t)r0 * NE);
    float4_* xdst = (float4_*)xs;
    #pragma unroll
    for (int i = tid; i < 400; i += 256) xdst[i] = xsrc[i];
  }
  { // stage W[3][100][64] -> LDS bf16, e-quad-major layout
    const int ch = tid >> 6, d = tid & 63;
    if (ch < 3) {
      const float* Ws = (ch == 0) ? Wq : (ch == 1) ? Wk : Wv;
      #pragma unroll 5
      for (int qd = 0; qd < 25; ++qd) {
        short4_ pk;
        #pragma unroll
        for (int jj = 0; jj < 4; ++jj)
          pk[jj] = (short)f2bf(Ws[(4*qd + jj)*ND + d]);
        *(short4_*)&Wl[ch][qd][d][0] = pk;
      }
    }
  }
  __syncthreads();

  const int wv = tid >> 6, lane = tid & 63;
  float aq[4] = {0,0,0,0}, ak[4] = {0,0,0,0}, av[4] = {0,0,0,0};
  const float* xw = xs + (wv * 4) * NE;

  for (int qd = 0; qd < 25; ++qd) {
    short4_ w4q = *(const short4_*)&Wl[0][qd][lane][0];
    short4_ w4k = *(const short4_*)&Wl[1][qd][lane][0];
    short4_ w4v = *(const short4_*)&Wl[2][qd][lane][0];
    float4_ x0 = *(const float4_*)&xw[0*NE + 4*qd];
    float4_ x1 = *(const float4_*)&xw[1*NE + 4*qd];
    float4_ x2 = *(const float4_*)&xw[2*NE + 4*qd];
    float4_ x3 = *(const float4_*)&xw[3*NE + 4*qd];
    #pragma unroll
    for (int jj = 0; jj < 4; ++jj) {
      float fq = bf2f(w4q[jj]), fk = bf2f(w4k[jj]), fv = bf2f(w4v[jj]);
      aq[0] += x0[jj]*fq; ak[0] += x0[jj]*fk; av[0] += x0[jj]*fv;
      aq[1] += x1[jj]*fq; ak[1] += x1[jj]*fk; av[1] += x1[jj]*fv;
      aq[2] += x2[jj]*fq; ak[2] += x2[jj]*fk; av[2] += x2[jj]*fv;
      aq[3] += x3[jj]*fq; ak[3] += x3[jj]*fk; av[3] += x3[jj]*fv;
    }
  }

  __syncthreads();   // xs reads done everywhere before Vl (alias) writes

  const float QS = 0.125f * 1.44269504088896340736f; // scale * log2(e)
  #pragma unroll
  for (int j = 0; j < 4; ++j) {
    int row = r0 + wv*4 + j;
    Qb[(size_t)row*ND + lane] = f2bf(aq[j] * QS);
    Kb[(size_t)row*ND + lane] = f2bf(ak[j]);
    Vl[wv*4 + j][lane] = f2bf(av[j]);
  }
  __syncthreads();

  if (tid < 128) { // transposed V write: 16B per thread
    int d = tid >> 1, halfi = tid & 1;
    short8 pk;
    #pragma unroll
    for (int k2 = 0; k2 < 8; ++k2) pk[k2] = (short)Vl[halfi*8 + k2][d];
    int b = r0 >> 12, tg = (r0 & (NT-1)) + halfi*8;
    *(short8*)(Vt + ((size_t)(b*ND + d))*NT + tg) = pk;
  }
}

// ---------------- causal flash attention ----------------
// 256 blocks x 2 waves. Block = uniform pair of 32-row q-groups (g, 127-g):
// exactly 65 kv-tiles/block. K/V staged in XOR-swizzled LDS (double-buffered);
// wave0 stages K, wave1 stages V; both consume. Register staging with
// issue-early / ds_write-late (T14). Defer-max online softmax (T13).
__global__ __launch_bounds__(128) void attn_kernel(
    const ushort_t* __restrict__ Qb,
    const ushort_t* __restrict__ Kb,
    const ushort_t* __restrict__ Vt,
    float* __restrict__ out) {
  __shared__ __align__(16) ushort_t Ks[2][64*64];
  __shared__ __align__(16) ushort_t Vs[2][64*64];
  __shared__ __align__(16) ushort_t Pbuf[2][16][72];

  const int tid  = threadIdx.x;
  const int w    = tid >> 6, lane = tid & 63;
  const int qrow = lane & 15, grp = lane >> 4;
  const int blk  = blockIdx.x;
  const int b    = blk >> 6;          // 64 pairs per batch
  const int pr   = blk & 63;
  const int srow8 = lane >> 3, sc16 = lane & 7;   // staging lane map

  const ushort_t* Kbase = Kb + (size_t)b*NT*ND;
  const ushort_t* Vtb   = Vt + (size_t)b*ND*NT;

  for (int half = 0; half < 2; ++half) {
    const int g  = half ? pr : (127 - pr);     // 32-row q-group index
    const int q0 = g << 5;
    const int nt = (g >> 1) + 1;               // kv tiles of 64
    const int qglob = q0 + 16*w + qrow;        // this lane's q row

    const ushort_t* Qr = Qb + ((size_t)(b*NT + q0 + 16*w + qrow))*ND + 8*grp;
    const short8 qf0 = *(const short8*)(Qr);
    const short8 qf1 = *(const short8*)(Qr + 32);

    float4_ O0 = {0,0,0,0}, O1 = {0,0,0,0}, O2 = {0,0,0,0}, O3 = {0,0,0,0};
    float m = -1e30f, lsum = 0.f;
    short8 sr[8];

    // prologue: stage tile 0
    #pragma unroll
    for (int i = 0; i < 8; ++i) {
      int row = 8*i + srow8;
      sr[i] = (w == 0)
        ? *(const short8*)(Kbase + (size_t)row*ND + sc16*8)
        : *(const short8*)(Vtb + (size_t)row*NT + sc16*8);
    }
    {
      ushort_t* dst = (w == 0) ? Ks[0] : Vs[0];
      #pragma unroll
      for (int i = 0; i < 8; ++i) {
        int row = 8*i + srow8;
        *(short8*)&dst[row*64 + ((sc16 ^ (row & 7)) << 3)] = sr[i];
      }
    }
    __syncthreads();

    for (int t = 0; t < nt; ++t) {
      const int cur = t & 1;
      const int kv0 = t << 6;

      if (t + 1 < nt) {  // issue next tile's global loads EARLY
        const int kn0 = kv0 + 64;
        #pragma unroll
        for (int i = 0; i < 8; ++i) {
          int row = 8*i + srow8;
          sr[i] = (w == 0)
            ? *(const short8*)(Kbase + (size_t)(kn0 + row)*ND + sc16*8)
            : *(const short8*)(Vtb + (size_t)row*NT + kn0 + sc16*8);
        }
      }

      const ushort_t* Kc = Ks[cur];
      const ushort_t* Vc = Vs[cur];

      // S^T = K_tile . Q^T  (lane owns q-row qglob; kv = kv0+st*16+grp*4+r)
      float4_ s[4];
      #pragma unroll
      for (int st = 0; st < 4; ++st) {
        int row = st*16 + qrow;
        short8 kf0 = *(const short8*)&Kc[row*64 + (((grp    ) ^ (row & 7)) << 3)];
        short8 kf1 = *(const short8*)&Kc[row*64 + (((grp + 4) ^ (row & 7)) << 3)];
        float4_ acc = {0,0,0,0};
        acc = __builtin_amdgcn_mfma_f32_16x16x32_bf16(kf0, qf0, acc, 0,0,0);
        acc = __builtin_amdgcn_mfma_f32_16x16x32_bf16(kf1, qf1, acc, 0,0,0);
        s[st] = acc;
      }

      // V fragments issued early: latency hides under softmax
      short8 vf[8];
      #pragma unroll
      for (int j = 0; j < 4; ++j) {
        int row = j*16 + qrow;
        vf[2*j]   = *(const short8*)&Vc[row*64 + (((grp    ) ^ (row & 7)) << 3)];
        vf[2*j+1] = *(const short8*)&Vc[row*64 + (((grp + 4) ^ (row & 7)) << 3)];
      }

      if (t == nt - 1) { // only diagonal tile violates causality
        #pragma unroll
        for (int st = 0; st < 4; ++st)
          #pragma unroll
          for (int r = 0; r < 4; ++r) {
            int kv = kv0 + st*16 + grp*4 + r;
            if (kv > qglob) s[st][r] = -1e30f;
          }
      }

      // online softmax (log2 domain), defer-max THR=8
      float pmax = s[0][0];
      #pragma unroll
      for (int st = 0; st < 4; ++st)
        #pragma unroll
        for (int r = 0; r < 4; ++r) pmax = fmaxf(pmax, s[st][r]);
      if (!__all(pmax <= m + 8.0f)) {
        float tm = pmax;
        tm = fmaxf(tm, __shfl_xor(tm, 16));
        tm = fmaxf(tm, __shfl_xor(tm, 32));
        const float mnew  = fmaxf(m, tm);
        const float alpha = fast_exp2(m - mnew);
        m = mnew;
        lsum *= alpha;
        #pragma unroll
        for (int r = 0; r < 4; ++r) {
          float ar = __shfl(alpha, grp*4 + r);
          O0[r] *= ar; O1[r] *= ar; O2[r] *= ar; O3[r] *= ar;
        }
      }

      float psum = 0.f;
      #pragma unroll
      for (int st = 0; st < 4; ++st) {
        short4_ pv;
        #pragma unroll
        for (int r = 0; r < 4; ++r) {
          float p = fast_exp2(s[st][r] - m);   // bounded by 2^8 when deferred
          psum += p;
          pv[r] = (short)f2bf(p);
        }
        *(short4_*)&Pbuf[w][qrow][st*16 + grp*4] = pv;
      }
      psum += __shfl_xor(psum, 16);
      psum += __shfl_xor(psum, 32);
      lsum += psum;

      asm volatile("s_waitcnt lgkmcnt(0)" ::: "memory");

      const short8 pf0 = *(const short8*)&Pbuf[w][qrow][8*grp];
      const short8 pf1 = *(const short8*)&Pbuf[w][qrow][32 + 8*grp];
      O0 = __builtin_amdgcn_mfma_f32_16x16x32_bf16(pf0, vf[0], O0, 0,0,0);
      O0 = __builtin_amdgcn_mfma_f32_16x16x32_bf16(pf1, vf[1], O0, 0,0,0);
      O1 = __builtin_amdgcn_mfma_f32_16x16x32_bf16(pf0, vf[2], O1, 0,0,0);
      O1 = __builtin_amdgcn_mfma_f32_16x16x32_bf16(pf1, vf[3], O1, 0,0,0);
      O2 = __builtin_amdgcn_mfma_f32_16x16x32_bf16(pf0, vf[4], O2, 0,0,0);
      O2 = __builtin_amdgcn_mfma_f32_16x16x32_bf16(pf1, vf[5], O2, 0,0,0);
      O3 = __builtin_amdgcn_mfma_f32_16x16x32_bf16(pf0, vf[6], O3, 0,0,0);
      O3 = __builtin_amdgcn_mfma_f32_16x16x32_bf16(pf1, vf[7], O3, 0,0,0);

      if (t + 1 < nt) {  // ds_write staged regs LATE (into the other buffer)
        ushort_t* dst = (w == 0) ? Ks[cur ^ 1] : Vs[cur ^ 1];
        #pragma unroll
        for (int i = 0; i < 8; ++i) {
          int row = 8*i + srow8;
          *(short8*)&dst[row*64 + ((sc16 ^ (row & 7)) << 3)] = sr[i];
        }
      }
      __syncthreads();
    }

    // epilogue: divide by row-sum, store directly (no cross-wave combine)
    float* orow = out + ((size_t)(b*NT + q0 + 16*w)) * ND;
    #pragma unroll
    for (int r = 0; r < 4; ++r) {
      float ls  = __shfl(lsum, grp*4 + r);
      float inv = 1.f / ls;
      int qr = grp*4 + r;
      orow[qr*ND + 0*16 + qrow] = O0[r]*inv;
      orow[qr*ND + 1*16 + qrow] = O1[r]*inv;
      orow[qr*ND + 2*16 + qrow] = O2[r]*inv;
      orow[qr*ND + 3*16 + qrow] = O3[r]*inv;
    }
  }
}

extern "C" void kernel_launch(void* const* d_in, const int* in_sizes, int n_in,
                              void* d_out, int out_size, void* d_ws, size_t ws_size,
                              hipStream_t stream) {
  const float* x  = (const float*)d_in[0];
  const float* Wq = (const float*)d_in[1];
  const float* Wk = (const float*)d_in[2];
  const float* Wv = (const float*)d_in[3];
  float* out = (float*)d_out;

  ushort_t* Qb = (ushort_t*)d_ws;                 // [B][T][64] bf16
  ushort_t* Kb = Qb + (size_t)NB*NT*ND;           // [B][T][64] bf16
  ushort_t* Vt = Kb + (size_t)NB*NT*ND;           // [B][64][T] bf16

  proj_kernel<<<dim3(1024), dim3(256), 0, stream>>>(x, Wq, Wk, Wv, Qb, Kb, Vt);
  attn_kernel<<<dim3(NB*64), dim3(128), 0, stream>>>(Qb, Kb, Vt, out);
}